// Round 11
// baseline (166.477 us; speedup 1.0000x reference)
//
#include <hip/hip_runtime.h>

#define N_PTS 1000000
#define H_DIM 200
#define W_DIM 70400
#define FILL_V -9999999.0f

// ws layout: counts[70400 int] | wpack[6656 bf16 = 13312 B] | list[70400][maxk] uint2
#define COUNTS_BYTES ((size_t)W_DIM * sizeof(int))
#define WPACK_ELEMS  6656
#define WPACK_BYTES  ((size_t)WPACK_ELEMS * 2)

typedef __attribute__((ext_vector_type(4))) float f32x4;
typedef __attribute__((ext_vector_type(8))) short bf16x8;

__device__ __forceinline__ unsigned bperm_u(unsigned src_lane, unsigned v) {
    return (unsigned)__builtin_amdgcn_ds_bpermute((int)(src_lane << 2), (int)v);
}
__device__ __forceinline__ unsigned cvt_pk_bf16(float lo, float hi) {
    unsigned d;
    asm("v_cvt_pk_bf16_f32 %0, %1, %2" : "=v"(d) : "v"(lo), "v"(hi));
    return d;
}
__device__ __forceinline__ bf16x8 mk_frag(unsigned d0, unsigned d1,
                                          unsigned d2, unsigned d3) {
    union { unsigned u[4]; bf16x8 s; } u;
    u.u[0] = d0; u.u[1] = d1; u.u[2] = d2; u.u[3] = d3;
    return u.s;
}

// ---------------------------------------------------------------------------
// Prep (R11 = R9 pack with kappa on A2 ONLY -- bisection of R10's inf).
// R10 (kappa on A2+A3+A4 + fused loop) -> inf; math re-derivation says the
// kappa relabeling is sound (R9's L3-kt0 fragment pins the (g,j)<->(g,j)
// slot pairing on all 32 slots), so the defect is mechanical. Bisect: ONLY
// the L2 path changes vs R9; A1/A3/A4 pack bit-identical to R9 (linear k).
// kappa(gk,j) for A2: j<4 -> f=4gk+j; j>=4 -> f=16+4gk+(j-4).
// Bias f=18 lands at (gk=0, j=6). All other fragments: k = gk*8+j linear.
//   A1 = W1eff[32][32]:  frags 0..1   (mtile), linear
//   A2 = W2eff[48][32]:  frags 2..4   (mtile), KAPPA
//   A3 = W3eff[48][64]:  frags 5..10  (mtile*2+kt), linear
//   A4 = W4eff[16][64]:  frags 11..12 (kt), linear, row 0 only
// A-frag: lane l holds row=(l&15), k-slot (gk=l>>4, j), dword p=j>>1,
// j even in low half.
// ---------------------------------------------------------------------------
__global__ void __launch_bounds__(256) pack_weights_kernel(
    const float* __restrict__ w1, const float* __restrict__ b1,
    const float* __restrict__ w2, const float* __restrict__ b2,
    const float* __restrict__ w3, const float* __restrict__ b3,
    const float* __restrict__ w4, const float* __restrict__ b4,
    unsigned short* __restrict__ wp)
{
    for (int idx = threadIdx.x; idx < WPACK_ELEMS; idx += 256) {
        const int rem  = idx & 511;
        const int lane = rem >> 3, j = rem & 7;
        const int c16 = lane & 15, gk = lane >> 4;
        const int kloc = gk * 8 + j;
        float v = 0.0f;
        if (idx < 1024) {                       // A1: linear (R9 exact)
            const int row = (idx >> 9) * 16 + c16, k = kloc;
            if (row < 18) v = (k < 4) ? w1[row * 4 + k] : (k == 4 ? b1[row] : 0.0f);
        } else if (idx < 2560) {                // A2: KAPPA
            const int row = ((idx - 1024) >> 9) * 16 + c16;
            const int f = (j < 4) ? (4 * gk + j) : (16 + 4 * gk + (j - 4));
            if (row < 36) v = (f < 18) ? w2[row * 18 + f] : (f == 18 ? b2[row] : 0.0f);
        } else if (idx < 5632) {                // A3: linear (R9 exact)
            const int f = (idx - 2560) >> 9;
            const int row = (f >> 1) * 16 + c16, k = (f & 1) * 32 + kloc;
            if (row < 36) v = (k < 36) ? w3[row * 36 + k] : (k == 36 ? b3[row] : 0.0f);
        } else {                                // A4: linear (R9 exact)
            const int row = c16, k = ((idx - 5632) >> 9) * 32 + kloc;
            if (row == 0) v = (k < 36) ? w4[k] : (k == 36 ? b4[0] : 0.0f);
        }
        const unsigned b = __float_as_uint(v);  // f32 -> bf16 RNE
        wp[idx] = (unsigned short)((b + 0x7FFFu + ((b >> 16) & 1u)) >> 16);
    }
}

// ---------------------------------------------------------------------------
// Kernel A v8 (R11): R9's verified body, with L2's B-fragment SELF-PACKED
// (kappa) instead of bperm-gathered. Everything else (L1, L3, L4, final
// redistribute, scatter) is VERBATIM R9 (passed, absmax 2.4e-3, 62us).
// L2 self-pack: B dwords = (P1[t][0][0], P1[t][0][1], P1[t][1][0],
// g==0 ? bias : P1[t][1][1]); discarded slot for g==0 was pack(relu(0),
// relu(0)) = 0 (W1eff rows 18,19 are zero-rows). Saves ~32 of ~140 bperms.
// If this PASSES -> kappa validated, L3/L4 next. If inf -> bug localized
// to the 20-line A2-kappa/B2-self-pack surface.
// ---------------------------------------------------------------------------
__global__ void __launch_bounds__(256) mlp_scatter_kernel(
    const float* __restrict__ input,        // [4][N]
    const int* __restrict__ tindex,         // [N][2] int32 (row, col)
    const unsigned short* __restrict__ wp,  // packed bf16 fragments
    int* __restrict__ counts,               // [W]
    uint2* __restrict__ list,               // [W][maxk]
    int maxk)
{
    if (tindex[0] == -1) return;            // empty-branch

    const int l   = threadIdx.x & 63;
    const int wav = (blockIdx.x * 256 + threadIdx.x) >> 6;
    const int base = wav << 6;
    if (base >= N_PTS) return;              // whole-wave early out (N%64==0)
    const int i = base + l;
    const int c16 = l & 15, g = l >> 4;

    // scatter-slot atomic first; latency hides under the GEMMs
    const int2 hw = ((const int2*)tindex)[i];
    const int pos = atomicAdd(&counts[hw.y], 1);

    // weight fragments (L1/L2-resident after first waves; 16B/lane each)
    const bf16x8* __restrict__ wf = (const bf16x8*)wp;
    const bf16x8 A1_0 = wf[0 * 64 + l], A1_1 = wf[1 * 64 + l];
    const bf16x8 A2_0 = wf[2 * 64 + l], A2_1 = wf[3 * 64 + l], A2_2 = wf[4 * 64 + l];
    const bf16x8 A3_00 = wf[5 * 64 + l], A3_01 = wf[6 * 64 + l];
    const bf16x8 A3_10 = wf[7 * 64 + l], A3_11 = wf[8 * 64 + l];
    const bf16x8 A3_20 = wf[9 * 64 + l], A3_21 = wf[10 * 64 + l];
    const bf16x8 A4_0 = wf[11 * 64 + l], A4_1 = wf[12 * 64 + l];

    const f32x4 zf = {0.0f, 0.0f, 0.0f, 0.0f};

    // x: lane p holds point base+p; pack to bf16 pairs (k0,k1) (k2,k3)
    const float x0 = input[0 * N_PTS + i], x1 = input[1 * N_PTS + i];
    const float x2 = input[2 * N_PTS + i], x3 = input[3 * N_PTS + i];
    const unsigned xp01 = cvt_pk_bf16(x0, x1);
    const unsigned xp23 = cvt_pk_bf16(x2, x3);

    // ---- L1: H1[18][64] (+pad) = A1 . [x;1;0...] ---- (R9 exact)
    unsigned P1[4][2][2];
#pragma unroll
    for (int t = 0; t < 4; ++t) {
        const unsigned srcl = (unsigned)(16 * t + c16);
        const unsigned bx0 = bperm_u(srcl, xp01);
        const unsigned bx1 = bperm_u(srcl, xp23);
        const unsigned d0 = (g == 0) ? bx0 : 0u;
        const unsigned d1 = (g == 0) ? bx1 : 0u;
        const unsigned d2 = (g == 0) ? 0x3F80u : 0u;   // k=4 -> 1.0 (bias row)
        const bf16x8 B = mk_frag(d0, d1, d2, 0u);
        const f32x4 D0 = __builtin_amdgcn_mfma_f32_16x16x32_bf16(A1_0, B, zf, 0, 0, 0);
        const f32x4 D1 = __builtin_amdgcn_mfma_f32_16x16x32_bf16(A1_1, B, zf, 0, 0, 0);
        P1[t][0][0] = cvt_pk_bf16(fmaxf(D0.x, 0.f), fmaxf(D0.y, 0.f));
        P1[t][0][1] = cvt_pk_bf16(fmaxf(D0.z, 0.f), fmaxf(D0.w, 0.f));
        P1[t][1][0] = cvt_pk_bf16(fmaxf(D1.x, 0.f), fmaxf(D1.y, 0.f));
        P1[t][1][1] = cvt_pk_bf16(fmaxf(D1.z, 0.f), fmaxf(D1.w, 0.f));
    }

    // ---- L2: H2[36][64] = A2 . [H1;1] -- KAPPA SELF-PACK (the R11 change)
    unsigned P2[4][3][2];
#pragma unroll
    for (int t = 0; t < 4; ++t) {
        const unsigned d0 = P1[t][0][0];                 // f = 4g+0, 4g+1
        const unsigned d1 = P1[t][0][1];                 // f = 4g+2, 4g+3
        const unsigned d2 = P1[t][1][0];                 // f = 16+4g+0, +1
        const unsigned d3 = (g == 0) ? 0x3F80u           // f=18 bias, f=19 pad
                                     : P1[t][1][1];      // f = 16+4g+2, +3
        const bf16x8 B = mk_frag(d0, d1, d2, d3);
        const f32x4 D0 = __builtin_amdgcn_mfma_f32_16x16x32_bf16(A2_0, B, zf, 0, 0, 0);
        const f32x4 D1 = __builtin_amdgcn_mfma_f32_16x16x32_bf16(A2_1, B, zf, 0, 0, 0);
        const f32x4 D2 = __builtin_amdgcn_mfma_f32_16x16x32_bf16(A2_2, B, zf, 0, 0, 0);
        P2[t][0][0] = cvt_pk_bf16(fmaxf(D0.x, 0.f), fmaxf(D0.y, 0.f));
        P2[t][0][1] = cvt_pk_bf16(fmaxf(D0.z, 0.f), fmaxf(D0.w, 0.f));
        P2[t][1][0] = cvt_pk_bf16(fmaxf(D1.x, 0.f), fmaxf(D1.y, 0.f));
        P2[t][1][1] = cvt_pk_bf16(fmaxf(D1.z, 0.f), fmaxf(D1.w, 0.f));
        P2[t][2][0] = cvt_pk_bf16(fmaxf(D2.x, 0.f), fmaxf(D2.y, 0.f));
        P2[t][2][1] = cvt_pk_bf16(fmaxf(D2.z, 0.f), fmaxf(D2.w, 0.f));
    }

    // ---- L3: H3[36][64] = A3 . [H2;1] (K=37 pad 64, 2 K-tiles) ---- (R9 exact)
    unsigned P3[4][3][2];
#pragma unroll
    for (int t = 0; t < 4; ++t) {
        unsigned dk0[4], dk1[4];
#pragma unroll
        for (int p = 0; p < 4; ++p) {
            const int Rl = (4 * g + p) & 7;
            const unsigned srcl = (unsigned)(c16 + 16 * (Rl >> 1));
            const unsigned lo = bperm_u(srcl, P2[t][0][p & 1]);
            const unsigned hi = bperm_u(srcl, P2[t][1][p & 1]);
            const unsigned m2 = bperm_u(srcl, P2[t][2][p & 1]);
            dk0[p] = (4 * g + p < 8) ? lo : hi;
            dk1[p] = (4 * g + p < 8) ? m2 : 0u;     // rows 48..63 = 0
        }
        if (g == 0) dk1[2] = (dk1[2] & 0xFFFF0000u) | 0x3F80u;  // act row 36 = 1.0
        const bf16x8 B0 = mk_frag(dk0[0], dk0[1], dk0[2], dk0[3]);
        const bf16x8 B1 = mk_frag(dk1[0], dk1[1], dk1[2], dk1[3]);
        f32x4 D0 = __builtin_amdgcn_mfma_f32_16x16x32_bf16(A3_00, B0, zf, 0, 0, 0);
        D0 = __builtin_amdgcn_mfma_f32_16x16x32_bf16(A3_01, B1, D0, 0, 0, 0);
        f32x4 D1 = __builtin_amdgcn_mfma_f32_16x16x32_bf16(A3_10, B0, zf, 0, 0, 0);
        D1 = __builtin_amdgcn_mfma_f32_16x16x32_bf16(A3_11, B1, D1, 0, 0, 0);
        f32x4 D2 = __builtin_amdgcn_mfma_f32_16x16x32_bf16(A3_20, B0, zf, 0, 0, 0);
        D2 = __builtin_amdgcn_mfma_f32_16x16x32_bf16(A3_21, B1, D2, 0, 0, 0);
        P3[t][0][0] = cvt_pk_bf16(fmaxf(D0.x, 0.f), fmaxf(D0.y, 0.f));
        P3[t][0][1] = cvt_pk_bf16(fmaxf(D0.z, 0.f), fmaxf(D0.w, 0.f));
        P3[t][1][0] = cvt_pk_bf16(fmaxf(D1.x, 0.f), fmaxf(D1.y, 0.f));
        P3[t][1][1] = cvt_pk_bf16(fmaxf(D1.z, 0.f), fmaxf(D1.w, 0.f));
        P3[t][2][0] = cvt_pk_bf16(fmaxf(D2.x, 0.f), fmaxf(D2.y, 0.f));
        P3[t][2][1] = cvt_pk_bf16(fmaxf(D2.z, 0.f), fmaxf(D2.w, 0.f));
    }

    // ---- L4: out[1][64] = A4 . [H3;1] ---- (R9 exact)
    float vout[4];
#pragma unroll
    for (int t = 0; t < 4; ++t) {
        unsigned dk0[4], dk1[4];
#pragma unroll
        for (int p = 0; p < 4; ++p) {
            const int Rl = (4 * g + p) & 7;
            const unsigned srcl = (unsigned)(c16 + 16 * (Rl >> 1));
            const unsigned lo = bperm_u(srcl, P3[t][0][p & 1]);
            const unsigned hi = bperm_u(srcl, P3[t][1][p & 1]);
            const unsigned m2 = bperm_u(srcl, P3[t][2][p & 1]);
            dk0[p] = (4 * g + p < 8) ? lo : hi;
            dk1[p] = (4 * g + p < 8) ? m2 : 0u;
        }
        if (g == 0) dk1[2] = (dk1[2] & 0xFFFF0000u) | 0x3F80u;  // act row 36 = 1.0
        const bf16x8 B0 = mk_frag(dk0[0], dk0[1], dk0[2], dk0[3]);
        const bf16x8 B1 = mk_frag(dk1[0], dk1[1], dk1[2], dk1[3]);
        f32x4 D = __builtin_amdgcn_mfma_f32_16x16x32_bf16(A4_0, B0, zf, 0, 0, 0);
        D = __builtin_amdgcn_mfma_f32_16x16x32_bf16(A4_1, B1, D, 0, 0, 0);
        vout[t] = D.x;                       // row 0 lives in lanes g==0, reg 0
    }

    // redistribute: point p's value sits in lane (p&15) of tile (p>>4)
    const unsigned r0 = bperm_u((unsigned)c16, __float_as_uint(vout[0]));
    const unsigned r1 = bperm_u((unsigned)c16, __float_as_uint(vout[1]));
    const unsigned r2 = bperm_u((unsigned)c16, __float_as_uint(vout[2]));
    const unsigned r3 = bperm_u((unsigned)c16, __float_as_uint(vout[3]));
    const unsigned vr = (g < 2) ? ((g == 0) ? r0 : r1) : ((g == 2) ? r2 : r3);

    if (pos < maxk) {   // never overflows statistically at maxk>=48
        uint2 e;
        e.x = vr;
        e.y = ((unsigned)i << 8) | (unsigned)hw.x;
        list[(size_t)hw.y * maxk + pos] = e;
    }
}

// Wave-local LDS ordering (colmax): drain this wave's DS ops.
__device__ __forceinline__ void lds_wave_fence() {
    asm volatile("s_waitcnt lgkmcnt(0)" ::: "memory");
}

// ---------------------------------------------------------------------------
// Kernel B (exact R4-verified version, passed R4/R8/R9): 32-bit dedup keys,
// native ds_max_u32, grid-stride 2200 blocks x 4 waves x 8 cols.
// ---------------------------------------------------------------------------
__global__ void __launch_bounds__(256) colmax_kernel(
    const int* __restrict__ tindex,
    const int* __restrict__ counts,
    const uint2* __restrict__ list,
    float* __restrict__ out,
    int maxk)
{
    __shared__ unsigned rowwin[4][200];
    const int lane = threadIdx.x;        // 0..63
    const int y    = threadIdx.y;        // 0..3
    unsigned* tbl = rowwin[y];

    const bool empty = (tindex[0] == -1);

    if (blockIdx.x == 0 && lane == 0 && y == 0)
        out[W_DIM] = empty ? 0.0f : 1.0f;    // flag output

    tbl[lane]       = 0u;
    tbl[lane + 64]  = 0u;
    tbl[lane + 128] = 0u;
    if (lane < 8) tbl[lane + 192] = 0u;
    lds_wave_fence();

    const int step = gridDim.x * 4;
    for (int w = blockIdx.x * 4 + y; w < W_DIM; w += step) {
        int c = 0;
        if (!empty) {
            c = counts[w];
            if (c > maxk) c = maxk;
        }

        uint2 e = make_uint2(0u, 0u);
        const bool have = (lane < c);
        float v = FILL_V;
        if (have) {
            e = list[(size_t)w * maxk + lane];
            atomicMax(&tbl[e.y & 0xFFu], e.y);   // native ds_max_u32
        }
        lds_wave_fence();
        if (have) {
            if (tbl[e.y & 0xFFu] == e.y)
                v = __uint_as_float(e.x);
            tbl[e.y & 0xFFu] = 0u;
        }
        lds_wave_fence();

#pragma unroll
        for (int off = 32; off > 0; off >>= 1)
            v = fmaxf(v, __shfl_down(v, off, 64));

        if (lane == 0) out[w] = v;
    }
}

extern "C" void kernel_launch(void* const* d_in, const int* in_sizes, int n_in,
                              void* d_out, int out_size, void* d_ws, size_t ws_size,
                              hipStream_t stream) {
    const float* input  = (const float*)d_in[0];
    const int*   tindex = (const int*)d_in[1];   // int32 on device
    const float* w1 = (const float*)d_in[2];
    const float* b1 = (const float*)d_in[3];
    const float* w2 = (const float*)d_in[4];
    const float* b2 = (const float*)d_in[5];
    const float* w3 = (const float*)d_in[6];
    const float* b3 = (const float*)d_in[7];
    const float* w4 = (const float*)d_in[8];
    const float* b4 = (const float*)d_in[9];
    float* out = (float*)d_out;

    int*            counts = (int*)d_ws;
    unsigned short* wpack  = (unsigned short*)((char*)d_ws + COUNTS_BYTES);
    uint2*          list   = (uint2*)((char*)d_ws + COUNTS_BYTES + WPACK_BYTES);

    size_t head = COUNTS_BYTES + WPACK_BYTES;
    size_t avail = (ws_size > head) ? ws_size - head : 0;
    int maxk = (int)(avail / ((size_t)W_DIM * sizeof(uint2)));
    if (maxk > 64) maxk = 64;
    if (maxk < 1)  maxk = 1;

    (void)hipMemsetAsync(counts, 0, COUNTS_BYTES, stream);

    pack_weights_kernel<<<1, 256, 0, stream>>>(w1, b1, w2, b2, w3, b3, w4, b4, wpack);

    // 1e6/64 = 15625 waves, 4 waves/block -> 3907 blocks
    mlp_scatter_kernel<<<(N_PTS / 64 + 3) / 4, 256, 0, stream>>>(
        input, tindex, wpack, counts, list, maxk);

    colmax_kernel<<<2200, dim3(64, 4), 0, stream>>>(
        tindex, counts, list, out, maxk);
}